// Round 3
// baseline (364.829 us; speedup 1.0000x reference)
//
#include <hip/hip_runtime.h>
#include <math.h>

// VectorExpansion: out[l, p, n] = sin(pi*x*n)/max(r,eps) * fc(r) * sqrt(2/rc) * x^l
// x = r/rc, rc=5, n=1..8, l=0..3.  r from pair geometry with periodic shift.
//
// Dtype post-mortems:
//  R1 (bf16 in / bf16 out) and R2 (fp32 in / bf16 out) failed IDENTICALLY
//  (error == max|ref| exactly -> 0 at ref argmax) -> common cause is the
//  OUTPUT dtype. Contract: output dtype follows the reference = float32.
//  Inputs are fp32 as the reference declares (dtype=jnp.float32).

#define RC_INV 0.2f
#define NORM 0.6324555320336759f  /* sqrt(2/5) */
#define PI_F 3.14159265358979323846f

__global__ __launch_bounds__(256) void ve_kernel(
    const float* __restrict__ positions,        // [N,3] fp32
    const float* __restrict__ cells,            // [S,3,3] fp32
    const int* __restrict__ cell_shifts,        // [P,3]
    const int* __restrict__ pairs,              // [P,2]
    const int* __restrict__ structure_pairs,    // [P]
    const int* __restrict__ structure_offsets,  // [S]
    float* __restrict__ out,                    // [4,P,8] fp32
    int P)
{
    const int p = blockIdx.x * blockDim.x + threadIdx.x;
    if (p >= P) return;

    const int s   = structure_pairs[p];
    const int off = structure_offsets[s];
    const int2 pr = ((const int2*)pairs)[p];
    const int ia = off + pr.x;
    const int ja = off + pr.y;

    const float shx = (float)cell_shifts[3*p + 0];
    const float shy = (float)cell_shifts[3*p + 1];
    const float shz = (float)cell_shifts[3*p + 2];

    // cells[s] row-major [c][d]; vec_d = dpos_d + sum_c shift[c]*cell[c][d]
    const float* C = cells + 9*s;
    const float vx = positions[3*ja+0] - positions[3*ia+0] + shx*C[0] + shy*C[3] + shz*C[6];
    const float vy = positions[3*ja+1] - positions[3*ia+1] + shx*C[1] + shy*C[4] + shz*C[7];
    const float vz = positions[3*ja+2] - positions[3*ia+2] + shx*C[2] + shy*C[5] + shz*C[8];

    const float r = sqrtf(vx*vx + vy*vy + vz*vz + 1e-12f);
    const float x = r * RC_INV;

    // out flat fp32 index (l,p,n) = l*P*8 + p*8 + n  ->  float4 slot (l*P+p)*2 + {0,1}
    float4* out4 = (float4*)out;

    if (!(x < 1.0f)) {
        // cutoff fc = 0 exactly -> all 32 outputs are exactly 0
        const float4 z = make_float4(0.f, 0.f, 0.f, 0.f);
        #pragma unroll
        for (int l = 0; l < 4; ++l) {
            const long long base = 2LL * (1LL*l*P + p);
            out4[base + 0] = z;
            out4[base + 1] = z;
        }
        return;
    }

    float s1, c1;
    sincosf(PI_F * x, &s1, &c1);
    const float fc   = 0.5f * (c1 + 1.0f);
    const float pref = fc * NORM / r;           // r >= 1e-6, safe

    // sin(n*pi*x) by Chebyshev recurrence: s_{n+1} = 2*cos(pi*x)*s_n - s_{n-1}
    float b[8];
    {
        float sm1 = 0.0f, sn = s1;
        const float twoc = 2.0f * c1;
        #pragma unroll
        for (int n = 0; n < 8; ++n) {
            b[n] = pref * sn;
            const float nxt = twoc * sn - sm1;
            sm1 = sn; sn = nxt;
        }
    }

    float xl = 1.0f;
    #pragma unroll
    for (int l = 0; l < 4; ++l) {
        const long long base = 2LL * (1LL*l*P + p);
        out4[base + 0] = make_float4(b[0]*xl, b[1]*xl, b[2]*xl, b[3]*xl);
        out4[base + 1] = make_float4(b[4]*xl, b[5]*xl, b[6]*xl, b[7]*xl);
        xl *= x;
    }
}

extern "C" void kernel_launch(void* const* d_in, const int* in_sizes, int n_in,
                              void* d_out, int out_size, void* d_ws, size_t ws_size,
                              hipStream_t stream) {
    const float* positions         = (const float*)d_in[0];
    const float* cells             = (const float*)d_in[1];
    const int*   cell_shifts       = (const int*)d_in[3];
    const int*   pairs             = (const int*)d_in[5];
    const int*   structure_pairs   = (const int*)d_in[7];
    const int*   structure_offsets = (const int*)d_in[8];
    float*       out               = (float*)d_out;

    const int P = in_sizes[7];          // structure_pairs is [P]
    const int block = 256;
    const int grid = (P + block - 1) / block;
    ve_kernel<<<grid, block, 0, stream>>>(positions, cells, cell_shifts, pairs,
                                          structure_pairs, structure_offsets, out, P);
}